// Round 7
// baseline (1279.226 us; speedup 1.0000x reference)
//
#include <hip/hip_runtime.h>

// MatrixMLP round 7: two-kernel split to keep f64 out of the hot path.
//  - Hot kernel (r6 wave-autonomous structure, zero __syncthreads):
//    f32 Cramer solve guarded by |det| > 2e-4*T^2  (T=||H||_F^2), which
//    guarantees smin/smax >= 2e-4 >> rcond  => no pinv truncation, and
//    kappa <= 5e3 => f32 accuracy sufficient.  No f64 => no spills.
//  - Repair kernel: re-checks the (slightly loosened) guard per row; for
//    the rare unsafe rows (~2-4%) redoes the solve in f64 (Cramer or
//    Jacobi+rcond-truncation, round-5 code) + scalar f32 MLP (round-4
//    code, previously passing) and overwrites those output rows.

typedef __attribute__((ext_vector_type(8))) short short8;
typedef __attribute__((ext_vector_type(4))) float f32x4;

__device__ __forceinline__ short f2bf(float f) {
  unsigned int u = __float_as_uint(f);
  u += 0x7fffu + ((u >> 16) & 1u);
  return (short)(u >> 16);
}

#define GUARD_THETA 2.0e-4f

// ---- per-wave LDS chunk (bytes); strides odd multiples of 16B ----
#define W_A    0        // 64 rows * 80 B  (A matrix, 32 bf16/row)
#define W_H1   5120     // 16 rows * 272 B
#define W_H2   9472     // 16 rows * 144 B
#define W_D    11776    // 64 rows * 20 B  (delta, 5-f32 stride)
#define W_SZ   13056
#define SMEM_SZ (4 * W_SZ)   // 52224 B -> 3 blocks/CU

// ---------------- weight fragment pre-pack ----------------
__global__ void pack_w(const float* __restrict__ W1, const float* __restrict__ W2,
                       const float* __restrict__ W3, short* __restrict__ ws)
{
  int t = blockIdx.x * 256 + threadIdx.x;
  if (t >= 26 * 64) return;
  int fid = t >> 6, lane = t & 63, l15 = lane & 15, lg = lane >> 4;
  short8 v;
  if (fid < 8) {
    int col = fid * 16 + l15;
    #pragma unroll
    for (int j = 0; j < 8; ++j) {
      int k = lg * 8 + j;
      v[j] = (k < 24) ? f2bf(W1[k * 128 + col]) : (short)0;
    }
  } else if (fid < 24) {
    int q = fid - 8, kt = q >> 2, nt = q & 3, col = nt * 16 + l15;
    #pragma unroll
    for (int j = 0; j < 8; ++j)
      v[j] = f2bf(W2[(kt * 32 + lg * 8 + j) * 64 + col]);
  } else {
    int kt = fid - 24;
    #pragma unroll
    for (int j = 0; j < 8; ++j)
      v[j] = (l15 < 4) ? f2bf(W3[(kt * 32 + lg * 8 + j) * 4 + l15]) : (short)0;
  }
  ((short8*)ws)[t] = v;
}

// ---------------- hot kernel ----------------
__global__ __launch_bounds__(256, 2) void MatrixMLP_54047868453544_kernel(
    const float* __restrict__ x,
    const float* __restrict__ W1, const float* __restrict__ b1,
    const float* __restrict__ W2, const float* __restrict__ b2,
    const float* __restrict__ W3, const float* __restrict__ b3,
    const short* __restrict__ wfrag,
    float* __restrict__ out, int Bn)
{
  __shared__ __align__(16) unsigned char smem[SMEM_SZ];
  const int tid  = threadIdx.x;
  const int lane = tid & 63;
  const int wv   = tid >> 6;
  const int l15  = lane & 15;
  const int lg   = lane >> 4;
  unsigned char* wsm = smem + wv * W_SZ;          // this wave's private LDS
  const long long g = (long long)blockIdx.x * 256 + wv * 64 + lane;
  const f32x4 fzero = {0.0f, 0.0f, 0.0f, 0.0f};

  // ---- load row (1 row/lane) ----
  float xf[20];
  if (g < Bn) {
    const float* xr = x + g * 20;
    #pragma unroll
    for (int i = 0; i < 5; ++i) {
      f32x4 v = *(const f32x4*)(xr + i * 4);
      xf[i*4+0] = v[0]; xf[i*4+1] = v[1]; xf[i*4+2] = v[2]; xf[i*4+3] = v[3];
    }
  } else {
    #pragma unroll
    for (int i = 0; i < 20; ++i) xf[i] = 0.0f;
  }

  // ---- f32 Cramer solve with safety guard (H[i][j] = x[j*4+i]) ----
  float xls[4];
  {
    float a00 = xf[0], a01 = xf[4], a02 = xf[8],  a03 = xf[12];
    float a10 = xf[1], a11 = xf[5], a12 = xf[9],  a13 = xf[13];
    float a20 = xf[2], a21 = xf[6], a22 = xf[10], a23 = xf[14];
    float a30 = xf[3], a31 = xf[7], a32 = xf[11], a33 = xf[15];
    float y0 = xf[16], y1 = xf[17], y2 = xf[18], y3 = xf[19];

    float s0 = a00*a11 - a10*a01, s1 = a00*a12 - a10*a02, s2 = a00*a13 - a10*a03;
    float s3 = a01*a12 - a11*a02, s4 = a01*a13 - a11*a03, s5 = a02*a13 - a12*a03;
    float c0 = a20*a31 - a30*a21, c1 = a20*a32 - a30*a22, c2 = a20*a33 - a30*a23;
    float c3 = a21*a32 - a31*a22, c4 = a21*a33 - a31*a23, c5 = a22*a33 - a32*a23;
    float det = s0*c5 - s1*c4 + s2*c3 + s3*c2 - s4*c1 + s5*c0;

    float T = a00*a00 + a01*a01 + a02*a02 + a03*a03
            + a10*a10 + a11*a11 + a12*a12 + a13*a13
            + a20*a20 + a21*a21 + a22*a22 + a23*a23
            + a30*a30 + a31*a31 + a32*a32 + a33*a33;

    float xd0 = 0.0f, xd1 = 0.0f, xd2 = 0.0f, xd3 = 0.0f;
    if (__builtin_fabsf(det) > GUARD_THETA * T * T) {
      float rdet = 1.0f / det;
      {
        float q0 =   a11*c5 - a12*c4 + a13*c3;
        float q1 = -(a01*c5 - a02*c4 + a03*c3);
        float q2 =   a31*s5 - a32*s4 + a33*s3;
        float q3 = -(a21*s5 - a22*s4 + a23*s3);
        xd0 = rdet * (q0*y0 + q1*y1 + q2*y2 + q3*y3);
      }
      {
        float q0 = -(a10*c5 - a12*c2 + a13*c1);
        float q1 =   a00*c5 - a02*c2 + a03*c1;
        float q2 = -(a30*s5 - a32*s2 + a33*s1);
        float q3 =   a20*s5 - a22*s2 + a23*s1;
        xd1 = rdet * (q0*y0 + q1*y1 + q2*y2 + q3*y3);
      }
      {
        float q0 =   a10*c4 - a11*c2 + a13*c0;
        float q1 = -(a00*c4 - a01*c2 + a03*c0);
        float q2 =   a30*s4 - a31*s2 + a33*s0;
        float q3 = -(a20*s4 - a21*s2 + a23*s0);
        xd2 = rdet * (q0*y0 + q1*y1 + q2*y2 + q3*y3);
      }
      {
        float q0 = -(a10*c3 - a11*c1 + a12*c0);
        float q1 =   a00*c3 - a01*c1 + a02*c0;
        float q2 = -(a30*s3 - a31*s1 + a32*s0);
        float q3 =   a20*s3 - a21*s1 + a22*s0;
        xd3 = rdet * (q0*y0 + q1*y1 + q2*y2 + q3*y3);
      }
    }
    // unsafe lanes keep xd=0: placeholder, repaired by the second kernel

    float xdv[4] = {xd0, xd1, xd2, xd3};
    short rowbuf[32];
    #pragma unroll
    for (int i = 0; i < 20; ++i) rowbuf[i] = f2bf(xf[i]);
    #pragma unroll
    for (int i = 0; i < 4; ++i) {
      float v = xdv[i];
      if (v != v) v = 0.0f;
      v = fminf(fmaxf(v, 0.0f), 1.0f);
      xls[i] = v;
      rowbuf[20 + i] = f2bf(v);
    }
    #pragma unroll
    for (int i = 24; i < 32; ++i) rowbuf[i] = 0;
    short8* dst = (short8*)(wsm + W_A + lane * 80);
    #pragma unroll
    for (int i = 0; i < 4; ++i) dst[i] = *(short8*)(rowbuf + i * 8);
  }

  // ---- weights + biases (loaded after solve to cap peak VGPR pressure) ----
  short8 bf1[8];
  const short8* wv4 = (const short8*)wfrag;
  if (wfrag) {
    #pragma unroll
    for (int nt = 0; nt < 8; ++nt) bf1[nt] = wv4[nt * 64 + lane];
  } else {
    #pragma unroll
    for (int nt = 0; nt < 8; ++nt) {
      int col = nt * 16 + l15;
      #pragma unroll
      for (int j = 0; j < 8; ++j) {
        int k = lg * 8 + j;
        bf1[nt][j] = (k < 24) ? f2bf(W1[k * 128 + col]) : (short)0;
      }
    }
  }
  float bias1[8], bias2[4], bias3;
  #pragma unroll
  for (int nt = 0; nt < 8; ++nt) bias1[nt] = b1[nt * 16 + l15];
  #pragma unroll
  for (int nt = 0; nt < 4; ++nt) bias2[nt] = b2[nt * 16 + l15];
  bias3 = b3[l15 & 3];

  asm volatile("s_waitcnt lgkmcnt(0)" ::: "memory");  // A-rows visible wave-wide

  // ---- four 16-row passes, wave-private, no barriers ----
  for (int t = 0; t < 4; ++t) {
    // layer 1: (16x32)@(32x128) + b1, ReLU -> H1 tile
    {
      short8 a = *(const short8*)(wsm + W_A + (t * 16 + l15) * 80 + lg * 16);
      f32x4 acc[8];
      #pragma unroll
      for (int nt = 0; nt < 8; ++nt)
        acc[nt] = __builtin_amdgcn_mfma_f32_16x16x32_bf16(a, bf1[nt], fzero, 0, 0, 0);
      #pragma unroll
      for (int nt = 0; nt < 8; ++nt) {
        #pragma unroll
        for (int j = 0; j < 4; ++j) {
          float h = acc[nt][j] + bias1[nt];
          h = h > 0.0f ? h : 0.0f;
          *(short*)(wsm + W_H1 + (lg * 4 + j) * 272 + (nt * 16 + l15) * 2) = f2bf(h);
        }
      }
    }
    asm volatile("s_waitcnt lgkmcnt(0)" ::: "memory");

    // layer 2: (16x128)@(128x64) + b2, ReLU -> H2 tile
    {
      f32x4 acc2[4] = {fzero, fzero, fzero, fzero};
      #pragma unroll
      for (int kt = 0; kt < 4; ++kt) {
        short8 a2 = *(const short8*)(wsm + W_H1 + l15 * 272 + kt * 64 + lg * 16);
        #pragma unroll
        for (int nt = 0; nt < 4; ++nt) {
          short8 bw;
          if (wfrag) bw = wv4[(8 + kt * 4 + nt) * 64 + lane];
          else {
            int col = nt * 16 + l15;
            #pragma unroll
            for (int j = 0; j < 8; ++j)
              bw[j] = f2bf(W2[(kt * 32 + lg * 8 + j) * 64 + col]);
          }
          acc2[nt] = __builtin_amdgcn_mfma_f32_16x16x32_bf16(a2, bw, acc2[nt], 0, 0, 0);
        }
      }
      #pragma unroll
      for (int nt = 0; nt < 4; ++nt) {
        #pragma unroll
        for (int j = 0; j < 4; ++j) {
          float h = acc2[nt][j] + bias2[nt];
          h = h > 0.0f ? h : 0.0f;
          *(short*)(wsm + W_H2 + (lg * 4 + j) * 144 + (nt * 16 + l15) * 2) = f2bf(h);
        }
      }
    }
    asm volatile("s_waitcnt lgkmcnt(0)" ::: "memory");

    // layer 3: (16x64)@(64x16[4]) + b3 -> delta
    {
      f32x4 acc3 = fzero;
      #pragma unroll
      for (int kt = 0; kt < 2; ++kt) {
        short8 a3 = *(const short8*)(wsm + W_H2 + l15 * 144 + kt * 64 + lg * 16);
        short8 bw;
        if (wfrag) bw = wv4[(24 + kt) * 64 + lane];
        else {
          #pragma unroll
          for (int j = 0; j < 8; ++j)
            bw[j] = (l15 < 4) ? f2bf(W3[(kt * 32 + lg * 8 + j) * 4 + l15]) : (short)0;
        }
        acc3 = __builtin_amdgcn_mfma_f32_16x16x32_bf16(a3, bw, acc3, 0, 0, 0);
      }
      if (l15 < 4) {
        #pragma unroll
        for (int j = 0; j < 4; ++j)
          *(float*)(wsm + W_D + (t * 16 + lg * 4 + j) * 20 + l15 * 4) = acc3[j] + bias3;
      }
    }
    // next pass's H1 writes are ordered behind this pass's reads (per-wave
    // DS ops are FIFO)
  }
  asm volatile("s_waitcnt lgkmcnt(0)" ::: "memory");

  // ---- epilogue: out = clip(x_ls + delta, 0, 1) ----
  if (g < Bn) {
    const unsigned char* dl = wsm + W_D + lane * 20;
    f32x4 o;
    #pragma unroll
    for (int c = 0; c < 4; ++c) {
      float v = xls[c] + *(const float*)(dl + c * 4);
      o[c] = fminf(fmaxf(v, 0.0f), 1.0f);
    }
    *(f32x4*)(out + g * 4) = o;
  }
}

// ---------------- repair kernel: rare ill-conditioned rows ----------------
__global__ __launch_bounds__(256) void repair_rows(
    const float* __restrict__ x,
    const float* __restrict__ W1, const float* __restrict__ b1,
    const float* __restrict__ W2, const float* __restrict__ b2,
    const float* __restrict__ W3, const float* __restrict__ b3,
    float* __restrict__ out, int Bn)
{
  int g = blockIdx.x * blockDim.x + threadIdx.x;
  if (g >= Bn) return;

  const float* xr = x + (long long)g * 20;
  float a[24];
  #pragma unroll
  for (int i = 0; i < 5; ++i) {
    float4 v = *(const float4*)(xr + i * 4);
    a[i*4+0] = v.x; a[i*4+1] = v.y; a[i*4+2] = v.z; a[i*4+3] = v.w;
  }

  // ---- same f32 guard as hot kernel, loosened 1.002x (superset repair) ----
  {
    float a00 = a[0], a01 = a[4], a02 = a[8],  a03 = a[12];
    float a10 = a[1], a11 = a[5], a12 = a[9],  a13 = a[13];
    float a20 = a[2], a21 = a[6], a22 = a[10], a23 = a[14];
    float a30 = a[3], a31 = a[7], a32 = a[11], a33 = a[15];
    float s0 = a00*a11 - a10*a01, s1 = a00*a12 - a10*a02, s2 = a00*a13 - a10*a03;
    float s3 = a01*a12 - a11*a02, s4 = a01*a13 - a11*a03, s5 = a02*a13 - a12*a03;
    float c0 = a20*a31 - a30*a21, c1 = a20*a32 - a30*a22, c2 = a20*a33 - a30*a23;
    float c3 = a21*a32 - a31*a22, c4 = a21*a33 - a31*a23, c5 = a22*a33 - a32*a23;
    float det = s0*c5 - s1*c4 + s2*c3 + s3*c2 - s4*c1 + s5*c0;
    float T = a00*a00 + a01*a01 + a02*a02 + a03*a03
            + a10*a10 + a11*a11 + a12*a12 + a13*a13
            + a20*a20 + a21*a21 + a22*a22 + a23*a23
            + a30*a30 + a31*a31 + a32*a32 + a33*a33;
    if (__builtin_fabsf(det) > GUARD_THETA * 1.002f * T * T) return;  // safe row
  }

  // ---- f64 solve (round-5 code): Cramer if provably un-truncated, else Jacobi ----
  double a00 = a[0], a01 = a[4], a02 = a[8],  a03 = a[12];
  double a10 = a[1], a11 = a[5], a12 = a[9],  a13 = a[13];
  double a20 = a[2], a21 = a[6], a22 = a[10], a23 = a[14];
  double a30 = a[3], a31 = a[7], a32 = a[11], a33 = a[15];
  double y0 = a[16], y1 = a[17], y2 = a[18], y3 = a[19];

  double s0 = a00*a11 - a10*a01, s1 = a00*a12 - a10*a02, s2 = a00*a13 - a10*a03;
  double s3 = a01*a12 - a11*a02, s4 = a01*a13 - a11*a03, s5 = a02*a13 - a12*a03;
  double c0 = a20*a31 - a30*a21, c1 = a20*a32 - a30*a22, c2 = a20*a33 - a30*a23;
  double c3 = a21*a32 - a31*a22, c4 = a21*a33 - a31*a23, c5 = a22*a33 - a32*a23;
  double det = s0*c5 - s1*c4 + s2*c3 + s3*c2 - s4*c1 + s5*c0;
  double T = a00*a00 + a01*a01 + a02*a02 + a03*a03
           + a10*a10 + a11*a11 + a12*a12 + a13*a13
           + a20*a20 + a21*a21 + a22*a22 + a23*a23
           + a30*a30 + a31*a31 + a32*a32 + a33*a33;

  double xd0 = 0.0, xd1 = 0.0, xd2 = 0.0, xd3 = 0.0;
  if (fabs(det) > 1.9073486328125e-5 * T * T) {   // 4*rcond: no truncation
    double rdet = 1.0 / det;
    {
      double q0 =   a11*c5 - a12*c4 + a13*c3;
      double q1 = -(a01*c5 - a02*c4 + a03*c3);
      double q2 =   a31*s5 - a32*s4 + a33*s3;
      double q3 = -(a21*s5 - a22*s4 + a23*s3);
      xd0 = rdet * (q0*y0 + q1*y1 + q2*y2 + q3*y3);
    }
    {
      double q0 = -(a10*c5 - a12*c2 + a13*c1);
      double q1 =   a00*c5 - a02*c2 + a03*c1;
      double q2 = -(a30*s5 - a32*s2 + a33*s1);
      double q3 =   a20*s5 - a22*s2 + a23*s1;
      xd1 = rdet * (q0*y0 + q1*y1 + q2*y2 + q3*y3);
    }
    {
      double q0 =   a10*c4 - a11*c2 + a13*c0;
      double q1 = -(a00*c4 - a01*c2 + a03*c0);
      double q2 =   a30*s4 - a31*s2 + a33*s0;
      double q3 = -(a20*s4 - a21*s2 + a23*s0);
      xd2 = rdet * (q0*y0 + q1*y1 + q2*y2 + q3*y3);
    }
    {
      double q0 = -(a10*c3 - a11*c1 + a12*c0);
      double q1 =   a00*c3 - a01*c1 + a02*c0;
      double q2 = -(a30*s3 - a31*s1 + a32*s0);
      double q3 =   a20*s3 - a21*s1 + a22*s0;
      xd3 = rdet * (q0*y0 + q1*y1 + q2*y2 + q3*y3);
    }
  } else {
    // f64 Jacobi eigensolve of G = H^T H with jax rcond truncation
    double G[4][4], V[4][4], rhs[4];
    #pragma unroll
    for (int p = 0; p < 4; ++p) {
      #pragma unroll
      for (int q = 0; q < 4; ++q) {
        double s = 0.0;
        #pragma unroll
        for (int i = 0; i < 4; ++i)
          s += (double)a[p * 4 + i] * (double)a[q * 4 + i];
        G[p][q] = s;
        V[p][q] = (p == q) ? 1.0 : 0.0;
      }
      double s = 0.0;
      #pragma unroll
      for (int i = 0; i < 4; ++i) s += (double)a[p * 4 + i] * (double)a[16 + i];
      rhs[p] = s;
    }
    #pragma unroll
    for (int sweep = 0; sweep < 6; ++sweep) {
      #pragma unroll
      for (int pq = 0; pq < 6; ++pq) {
        constexpr int PP[6] = {0, 0, 0, 1, 1, 2};
        constexpr int QQ[6] = {1, 2, 3, 2, 3, 3};
        const int p = PP[pq], q = QQ[pq];
        double apq = G[p][q];
        double c, s;
        if (apq != 0.0) {
          double tau = (G[q][q] - G[p][p]) / (2.0 * apq);
          double t = (tau >= 0.0 ? 1.0 : -1.0) / (fabs(tau) + sqrt(1.0 + tau * tau));
          c = 1.0 / sqrt(1.0 + t * t);
          s = t * c;
        } else { c = 1.0; s = 0.0; }
        #pragma unroll
        for (int k = 0; k < 4; ++k) {
          double gpk = G[p][k], gqk = G[q][k];
          G[p][k] = c * gpk - s * gqk;
          G[q][k] = s * gpk + c * gqk;
        }
        #pragma unroll
        for (int k = 0; k < 4; ++k) {
          double gkp = G[k][p], gkq = G[k][q];
          G[k][p] = c * gkp - s * gkq;
          G[k][q] = s * gkp + c * gkq;
        }
        #pragma unroll
        for (int k = 0; k < 4; ++k) {
          double vkp = V[k][p], vkq = V[k][q];
          V[k][p] = c * vkp - s * vkq;
          V[k][q] = s * vkp + c * vkq;
        }
      }
    }
    double lam[4] = {G[0][0], G[1][1], G[2][2], G[3][3]};
    double lmax = fmax(fmax(lam[0], lam[1]), fmax(lam[2], lam[3]));
    lmax = fmax(lmax, 0.0);
    const double cut = 2.27373675443232e-11 * lmax;  // (4.7683716e-6)^2
    #pragma unroll
    for (int i = 0; i < 4; ++i) {
      if (lam[i] > cut && lam[i] > 0.0) {
        double coef = (V[0][i] * rhs[0] + V[1][i] * rhs[1] +
                       V[2][i] * rhs[2] + V[3][i] * rhs[3]) / lam[i];
        xd0 += V[0][i] * coef;
        xd1 += V[1][i] * coef;
        xd2 += V[2][i] * coef;
        xd3 += V[3][i] * coef;
      }
    }
  }

  float xls[4];
  {
    double xd[4] = {xd0, xd1, xd2, xd3};
    #pragma unroll
    for (int i = 0; i < 4; ++i) {
      float v = (float)xd[i];
      if (v != v) v = 0.0f;
      v = fminf(fmaxf(v, 0.0f), 1.0f);
      xls[i] = v;
      a[20 + i] = v;
    }
  }

  // ---- scalar f32 MLP (round-4 code, previously passing) ----
  float acc2[64];
  #pragma unroll
  for (int m = 0; m < 64; ++m) acc2[m] = b2[m];
  for (int j = 0; j < 128; ++j) {
    float t = b1[j];
    #pragma unroll
    for (int k = 0; k < 24; ++k) t = fmaf(a[k], W1[k * 128 + j], t);
    t = fmaxf(t, 0.0f);
    #pragma unroll
    for (int m = 0; m < 64; ++m) acc2[m] = fmaf(t, W2[j * 64 + m], acc2[m]);
  }
  float delta[4] = {b3[0], b3[1], b3[2], b3[3]};
  #pragma unroll
  for (int m = 0; m < 64; ++m) {
    float h = fmaxf(acc2[m], 0.0f);
    #pragma unroll
    for (int c = 0; c < 4; ++c) delta[c] = fmaf(h, W3[m * 4 + c], delta[c]);
  }
  float4 o;
  o.x = fminf(fmaxf(xls[0] + delta[0], 0.0f), 1.0f);
  o.y = fminf(fmaxf(xls[1] + delta[1], 0.0f), 1.0f);
  o.z = fminf(fmaxf(xls[2] + delta[2], 0.0f), 1.0f);
  o.w = fminf(fmaxf(xls[3] + delta[3], 0.0f), 1.0f);
  *(float4*)(out + (long long)g * 4) = o;
}

extern "C" void kernel_launch(void* const* d_in, const int* in_sizes, int n_in,
                              void* d_out, int out_size, void* d_ws, size_t ws_size,
                              hipStream_t stream) {
  (void)n_in;
  const float* x  = (const float*)d_in[0];
  const float* W1 = (const float*)d_in[1];
  const float* b1 = (const float*)d_in[2];
  const float* W2 = (const float*)d_in[3];
  const float* b2 = (const float*)d_in[4];
  const float* W3 = (const float*)d_in[5];
  const float* b3 = (const float*)d_in[6];
  float* out = (float*)d_out;
  const int Bn = in_sizes[0] / 20;

  short* wfrag = nullptr;
  if (ws_size >= (size_t)(26 * 64 * 16)) {
    wfrag = (short*)d_ws;
    pack_w<<<7, 256, 0, stream>>>(W1, W2, W3, wfrag);
  }

  (void)hipGetLastError();
  const int nblk = (Bn + 255) / 256;
  MatrixMLP_54047868453544_kernel<<<nblk, 256, 0, stream>>>(
      x, W1, b1, W2, b2, W3, b3, wfrag, out, Bn);
  const int rblk = (Bn + 255) / 256;
  repair_rows<<<rblk, 256, 0, stream>>>(x, W1, b1, W2, b2, W3, b3, out, Bn);
  hipError_t e = hipGetLastError();
  if (e != hipSuccess) {
    int byte = 0x40 + ((int)e & 63);
    hipMemsetAsync(d_out, byte, (size_t)out_size * sizeof(float), stream);
  }
}

// Round 8
// 372.276 us; speedup vs baseline: 3.4362x; 3.4362x over previous
//
#include <hip/hip_runtime.h>

// MatrixMLP round 8: worklist-compacted repair.
//  - Hot kernel: unchanged r7 structure (wave-autonomous, f32 Cramer solve
//    guarded by |det| > 2e-4*T^2, bf16-MFMA MLP).  Unsafe lanes additionally
//    append their row id to a worklist in d_ws (atomicAdd; set is
//    deterministic, order irrelevant -- each entry repairs only its own row).
//  - Repair kernel: fixed 256-block grid striding over the DENSE worklist
//    (~3.7% of rows) => every repair wave 100% active.  r7's divergence bug
//    (91% of waves paying the f64+MLP path for ~2 lanes) is gone.
//  - Repair math byte-identical to r7: f64 det -> Cramer (no truncation
//    possible) or Jacobi eigensolve + jax rcond cut; scalar f32 MLP.

typedef __attribute__((ext_vector_type(8))) short short8;
typedef __attribute__((ext_vector_type(4))) float f32x4;

__device__ __forceinline__ short f2bf(float f) {
  unsigned int u = __float_as_uint(f);
  u += 0x7fffu + ((u >> 16) & 1u);
  return (short)(u >> 16);
}

#define GUARD_THETA 2.0e-4f
#define WFRAG_BYTES 26624        // 26 frags * 64 lanes * 16 B
#define WL_CNT_OFF  26624        // one int
#define WL_LIST_OFF 26656        // Bn ints

// ---- per-wave LDS chunk (bytes); strides odd multiples of 16B ----
#define W_A    0        // 64 rows * 80 B  (A matrix, 32 bf16/row)
#define W_H1   5120     // 16 rows * 272 B
#define W_H2   9472     // 16 rows * 144 B
#define W_D    11776    // 64 rows * 20 B  (delta, 5-f32 stride)
#define W_SZ   13056
#define SMEM_SZ (4 * W_SZ)   // 52224 B -> 3 blocks/CU

// ---------------- weight fragment pre-pack (+ worklist counter reset) -------
__global__ void pack_w(const float* __restrict__ W1, const float* __restrict__ W2,
                       const float* __restrict__ W3, short* __restrict__ ws,
                       int* __restrict__ wl_cnt)
{
  if (wl_cnt && blockIdx.x == 0 && threadIdx.x == 0) *wl_cnt = 0;
  int t = blockIdx.x * 256 + threadIdx.x;
  if (t >= 26 * 64) return;
  int fid = t >> 6, lane = t & 63, l15 = lane & 15, lg = lane >> 4;
  short8 v;
  if (fid < 8) {
    int col = fid * 16 + l15;
    #pragma unroll
    for (int j = 0; j < 8; ++j) {
      int k = lg * 8 + j;
      v[j] = (k < 24) ? f2bf(W1[k * 128 + col]) : (short)0;
    }
  } else if (fid < 24) {
    int q = fid - 8, kt = q >> 2, nt = q & 3, col = nt * 16 + l15;
    #pragma unroll
    for (int j = 0; j < 8; ++j)
      v[j] = f2bf(W2[(kt * 32 + lg * 8 + j) * 64 + col]);
  } else {
    int kt = fid - 24;
    #pragma unroll
    for (int j = 0; j < 8; ++j)
      v[j] = (l15 < 4) ? f2bf(W3[(kt * 32 + lg * 8 + j) * 4 + l15]) : (short)0;
  }
  ((short8*)ws)[t] = v;
}

// ---------------- hot kernel ----------------
__global__ __launch_bounds__(256, 2) void MatrixMLP_54047868453544_kernel(
    const float* __restrict__ x,
    const float* __restrict__ W1, const float* __restrict__ b1,
    const float* __restrict__ W2, const float* __restrict__ b2,
    const float* __restrict__ W3, const float* __restrict__ b3,
    const short* __restrict__ wfrag,
    int* __restrict__ wl_cnt, int* __restrict__ wl_list,
    float* __restrict__ out, int Bn)
{
  __shared__ __align__(16) unsigned char smem[SMEM_SZ];
  const int tid  = threadIdx.x;
  const int lane = tid & 63;
  const int wv   = tid >> 6;
  const int l15  = lane & 15;
  const int lg   = lane >> 4;
  unsigned char* wsm = smem + wv * W_SZ;          // this wave's private LDS
  const long long g = (long long)blockIdx.x * 256 + wv * 64 + lane;
  const f32x4 fzero = {0.0f, 0.0f, 0.0f, 0.0f};

  // ---- load row (1 row/lane) ----
  float xf[20];
  if (g < Bn) {
    const float* xr = x + g * 20;
    #pragma unroll
    for (int i = 0; i < 5; ++i) {
      f32x4 v = *(const f32x4*)(xr + i * 4);
      xf[i*4+0] = v[0]; xf[i*4+1] = v[1]; xf[i*4+2] = v[2]; xf[i*4+3] = v[3];
    }
  } else {
    #pragma unroll
    for (int i = 0; i < 20; ++i) xf[i] = 0.0f;
  }

  // ---- f32 Cramer solve with safety guard (H[i][j] = x[j*4+i]) ----
  float xls[4];
  {
    float a00 = xf[0], a01 = xf[4], a02 = xf[8],  a03 = xf[12];
    float a10 = xf[1], a11 = xf[5], a12 = xf[9],  a13 = xf[13];
    float a20 = xf[2], a21 = xf[6], a22 = xf[10], a23 = xf[14];
    float a30 = xf[3], a31 = xf[7], a32 = xf[11], a33 = xf[15];
    float y0 = xf[16], y1 = xf[17], y2 = xf[18], y3 = xf[19];

    float s0 = a00*a11 - a10*a01, s1 = a00*a12 - a10*a02, s2 = a00*a13 - a10*a03;
    float s3 = a01*a12 - a11*a02, s4 = a01*a13 - a11*a03, s5 = a02*a13 - a12*a03;
    float c0 = a20*a31 - a30*a21, c1 = a20*a32 - a30*a22, c2 = a20*a33 - a30*a23;
    float c3 = a21*a32 - a31*a22, c4 = a21*a33 - a31*a23, c5 = a22*a33 - a32*a23;
    float det = s0*c5 - s1*c4 + s2*c3 + s3*c2 - s4*c1 + s5*c0;

    float T = a00*a00 + a01*a01 + a02*a02 + a03*a03
            + a10*a10 + a11*a11 + a12*a12 + a13*a13
            + a20*a20 + a21*a21 + a22*a22 + a23*a23
            + a30*a30 + a31*a31 + a32*a32 + a33*a33;

    const bool safe = __builtin_fabsf(det) > GUARD_THETA * T * T;
    float xd0 = 0.0f, xd1 = 0.0f, xd2 = 0.0f, xd3 = 0.0f;
    if (safe) {
      float rdet = 1.0f / det;
      {
        float q0 =   a11*c5 - a12*c4 + a13*c3;
        float q1 = -(a01*c5 - a02*c4 + a03*c3);
        float q2 =   a31*s5 - a32*s4 + a33*s3;
        float q3 = -(a21*s5 - a22*s4 + a23*s3);
        xd0 = rdet * (q0*y0 + q1*y1 + q2*y2 + q3*y3);
      }
      {
        float q0 = -(a10*c5 - a12*c2 + a13*c1);
        float q1 =   a00*c5 - a02*c2 + a03*c1;
        float q2 = -(a30*s5 - a32*s2 + a33*s1);
        float q3 =   a20*s5 - a22*s2 + a23*s1;
        xd1 = rdet * (q0*y0 + q1*y1 + q2*y2 + q3*y3);
      }
      {
        float q0 =   a10*c4 - a11*c2 + a13*c0;
        float q1 = -(a00*c4 - a01*c2 + a03*c0);
        float q2 =   a30*s4 - a31*s2 + a33*s0;
        float q3 = -(a20*s4 - a21*s2 + a23*s0);
        xd2 = rdet * (q0*y0 + q1*y1 + q2*y2 + q3*y3);
      }
      {
        float q0 = -(a10*c3 - a11*c1 + a12*c0);
        float q1 =   a00*c3 - a01*c1 + a02*c0;
        float q2 = -(a30*s3 - a31*s1 + a32*s0);
        float q3 =   a20*s3 - a21*s1 + a22*s0;
        xd3 = rdet * (q0*y0 + q1*y1 + q2*y2 + q3*y3);
      }
    } else if (wl_list && g < Bn) {
      // append this row to the repair worklist (placeholder xls stays 0)
      int idx = atomicAdd(wl_cnt, 1);
      wl_list[idx] = (int)g;
    }

    float xdv[4] = {xd0, xd1, xd2, xd3};
    short rowbuf[32];
    #pragma unroll
    for (int i = 0; i < 20; ++i) rowbuf[i] = f2bf(xf[i]);
    #pragma unroll
    for (int i = 0; i < 4; ++i) {
      float v = xdv[i];
      if (v != v) v = 0.0f;
      v = fminf(fmaxf(v, 0.0f), 1.0f);
      xls[i] = v;
      rowbuf[20 + i] = f2bf(v);
    }
    #pragma unroll
    for (int i = 24; i < 32; ++i) rowbuf[i] = 0;
    short8* dst = (short8*)(wsm + W_A + lane * 80);
    #pragma unroll
    for (int i = 0; i < 4; ++i) dst[i] = *(short8*)(rowbuf + i * 8);
  }

  // ---- weights + biases ----
  short8 bf1[8];
  const short8* wv4 = (const short8*)wfrag;
  if (wfrag) {
    #pragma unroll
    for (int nt = 0; nt < 8; ++nt) bf1[nt] = wv4[nt * 64 + lane];
  } else {
    #pragma unroll
    for (int nt = 0; nt < 8; ++nt) {
      int col = nt * 16 + l15;
      #pragma unroll
      for (int j = 0; j < 8; ++j) {
        int k = lg * 8 + j;
        bf1[nt][j] = (k < 24) ? f2bf(W1[k * 128 + col]) : (short)0;
      }
    }
  }
  float bias1[8], bias2[4], bias3;
  #pragma unroll
  for (int nt = 0; nt < 8; ++nt) bias1[nt] = b1[nt * 16 + l15];
  #pragma unroll
  for (int nt = 0; nt < 4; ++nt) bias2[nt] = b2[nt * 16 + l15];
  bias3 = b3[l15 & 3];

  asm volatile("s_waitcnt lgkmcnt(0)" ::: "memory");  // A-rows visible wave-wide

  // ---- four 16-row passes, wave-private, no barriers ----
  for (int t = 0; t < 4; ++t) {
    // layer 1: (16x32)@(32x128) + b1, ReLU -> H1 tile
    {
      short8 a = *(const short8*)(wsm + W_A + (t * 16 + l15) * 80 + lg * 16);
      f32x4 acc[8];
      #pragma unroll
      for (int nt = 0; nt < 8; ++nt)
        acc[nt] = __builtin_amdgcn_mfma_f32_16x16x32_bf16(a, bf1[nt], fzero, 0, 0, 0);
      #pragma unroll
      for (int nt = 0; nt < 8; ++nt) {
        #pragma unroll
        for (int j = 0; j < 4; ++j) {
          float h = acc[nt][j] + bias1[nt];
          h = h > 0.0f ? h : 0.0f;
          *(short*)(wsm + W_H1 + (lg * 4 + j) * 272 + (nt * 16 + l15) * 2) = f2bf(h);
        }
      }
    }
    asm volatile("s_waitcnt lgkmcnt(0)" ::: "memory");

    // layer 2: (16x128)@(128x64) + b2, ReLU -> H2 tile
    {
      f32x4 acc2[4] = {fzero, fzero, fzero, fzero};
      #pragma unroll
      for (int kt = 0; kt < 4; ++kt) {
        short8 a2 = *(const short8*)(wsm + W_H1 + l15 * 272 + kt * 64 + lg * 16);
        #pragma unroll
        for (int nt = 0; nt < 4; ++nt) {
          short8 bw;
          if (wfrag) bw = wv4[(8 + kt * 4 + nt) * 64 + lane];
          else {
            int col = nt * 16 + l15;
            #pragma unroll
            for (int j = 0; j < 8; ++j)
              bw[j] = f2bf(W2[(kt * 32 + lg * 8 + j) * 64 + col]);
          }
          acc2[nt] = __builtin_amdgcn_mfma_f32_16x16x32_bf16(a2, bw, acc2[nt], 0, 0, 0);
        }
      }
      #pragma unroll
      for (int nt = 0; nt < 4; ++nt) {
        #pragma unroll
        for (int j = 0; j < 4; ++j) {
          float h = acc2[nt][j] + bias2[nt];
          h = h > 0.0f ? h : 0.0f;
          *(short*)(wsm + W_H2 + (lg * 4 + j) * 144 + (nt * 16 + l15) * 2) = f2bf(h);
        }
      }
    }
    asm volatile("s_waitcnt lgkmcnt(0)" ::: "memory");

    // layer 3: (16x64)@(64x16[4]) + b3 -> delta
    {
      f32x4 acc3 = fzero;
      #pragma unroll
      for (int kt = 0; kt < 2; ++kt) {
        short8 a3 = *(const short8*)(wsm + W_H2 + l15 * 144 + kt * 64 + lg * 16);
        short8 bw;
        if (wfrag) bw = wv4[(24 + kt) * 64 + lane];
        else {
          #pragma unroll
          for (int j = 0; j < 8; ++j)
            bw[j] = (l15 < 4) ? f2bf(W3[(kt * 32 + lg * 8 + j) * 4 + l15]) : (short)0;
        }
        acc3 = __builtin_amdgcn_mfma_f32_16x16x32_bf16(a3, bw, acc3, 0, 0, 0);
      }
      if (l15 < 4) {
        #pragma unroll
        for (int j = 0; j < 4; ++j)
          *(float*)(wsm + W_D + (t * 16 + lg * 4 + j) * 20 + l15 * 4) = acc3[j] + bias3;
      }
    }
  }
  asm volatile("s_waitcnt lgkmcnt(0)" ::: "memory");

  // ---- epilogue: out = clip(x_ls + delta, 0, 1) ----
  if (g < Bn) {
    const unsigned char* dl = wsm + W_D + lane * 20;
    f32x4 o;
    #pragma unroll
    for (int c = 0; c < 4; ++c) {
      float v = xls[c] + *(const float*)(dl + c * 4);
      o[c] = fminf(fmaxf(v, 0.0f), 1.0f);
    }
    *(f32x4*)(out + g * 4) = o;
  }
}

// ---------------- repair kernel ----------------
// use_wl=1: grid-stride over the dense worklist (every lane active).
// use_wl=0: fallback full scan with guard recheck (r7 behavior).
__global__ __launch_bounds__(256) void repair_rows(
    const float* __restrict__ x,
    const float* __restrict__ W1, const float* __restrict__ b1,
    const float* __restrict__ W2, const float* __restrict__ b2,
    const float* __restrict__ W3, const float* __restrict__ b3,
    float* __restrict__ out, int Bn,
    const int* __restrict__ wl_cnt, const int* __restrict__ wl_list,
    int use_wl)
{
  const int nthr = gridDim.x * blockDim.x;
  const int t0 = blockIdx.x * blockDim.x + threadIdx.x;
  const int count = use_wl ? *wl_cnt : Bn;

  for (int i = t0; i < count; i += nthr) {
    const int g = use_wl ? wl_list[i] : i;

    const float* xr = x + (long long)g * 20;
    float a[24];
    #pragma unroll
    for (int ii = 0; ii < 5; ++ii) {
      float4 v = *(const float4*)(xr + ii * 4);
      a[ii*4+0] = v.x; a[ii*4+1] = v.y; a[ii*4+2] = v.z; a[ii*4+3] = v.w;
    }

    if (!use_wl) {
      // fallback: recheck the (loosened) f32 guard; skip safe rows
      float a00 = a[0], a01 = a[4], a02 = a[8],  a03 = a[12];
      float a10 = a[1], a11 = a[5], a12 = a[9],  a13 = a[13];
      float a20 = a[2], a21 = a[6], a22 = a[10], a23 = a[14];
      float a30 = a[3], a31 = a[7], a32 = a[11], a33 = a[15];
      float s0 = a00*a11 - a10*a01, s1 = a00*a12 - a10*a02, s2 = a00*a13 - a10*a03;
      float s3 = a01*a12 - a11*a02, s4 = a01*a13 - a11*a03, s5 = a02*a13 - a12*a03;
      float c0 = a20*a31 - a30*a21, c1 = a20*a32 - a30*a22, c2 = a20*a33 - a30*a23;
      float c3 = a21*a32 - a31*a22, c4 = a21*a33 - a31*a23, c5 = a22*a33 - a32*a23;
      float det = s0*c5 - s1*c4 + s2*c3 + s3*c2 - s4*c1 + s5*c0;
      float T = a00*a00 + a01*a01 + a02*a02 + a03*a03
              + a10*a10 + a11*a11 + a12*a12 + a13*a13
              + a20*a20 + a21*a21 + a22*a22 + a23*a23
              + a30*a30 + a31*a31 + a32*a32 + a33*a33;
      if (__builtin_fabsf(det) > GUARD_THETA * 1.002f * T * T) continue;
    }

    // ---- f64 solve: Cramer if provably un-truncated, else Jacobi+rcond ----
    double a00 = a[0], a01 = a[4], a02 = a[8],  a03 = a[12];
    double a10 = a[1], a11 = a[5], a12 = a[9],  a13 = a[13];
    double a20 = a[2], a21 = a[6], a22 = a[10], a23 = a[14];
    double a30 = a[3], a31 = a[7], a32 = a[11], a33 = a[15];
    double y0 = a[16], y1 = a[17], y2 = a[18], y3 = a[19];

    double s0 = a00*a11 - a10*a01, s1 = a00*a12 - a10*a02, s2 = a00*a13 - a10*a03;
    double s3 = a01*a12 - a11*a02, s4 = a01*a13 - a11*a03, s5 = a02*a13 - a12*a03;
    double c0 = a20*a31 - a30*a21, c1 = a20*a32 - a30*a22, c2 = a20*a33 - a30*a23;
    double c3 = a21*a32 - a31*a22, c4 = a21*a33 - a31*a23, c5 = a22*a33 - a32*a23;
    double det = s0*c5 - s1*c4 + s2*c3 + s3*c2 - s4*c1 + s5*c0;
    double T = a00*a00 + a01*a01 + a02*a02 + a03*a03
             + a10*a10 + a11*a11 + a12*a12 + a13*a13
             + a20*a20 + a21*a21 + a22*a22 + a23*a23
             + a30*a30 + a31*a31 + a32*a32 + a33*a33;

    double xd0 = 0.0, xd1 = 0.0, xd2 = 0.0, xd3 = 0.0;
    if (fabs(det) > 1.9073486328125e-5 * T * T) {   // 4*rcond: no truncation
      double rdet = 1.0 / det;
      {
        double q0 =   a11*c5 - a12*c4 + a13*c3;
        double q1 = -(a01*c5 - a02*c4 + a03*c3);
        double q2 =   a31*s5 - a32*s4 + a33*s3;
        double q3 = -(a21*s5 - a22*s4 + a23*s3);
        xd0 = rdet * (q0*y0 + q1*y1 + q2*y2 + q3*y3);
      }
      {
        double q0 = -(a10*c5 - a12*c2 + a13*c1);
        double q1 =   a00*c5 - a02*c2 + a03*c1;
        double q2 = -(a30*s5 - a32*s2 + a33*s1);
        double q3 =   a20*s5 - a22*s2 + a23*s1;
        xd1 = rdet * (q0*y0 + q1*y1 + q2*y2 + q3*y3);
      }
      {
        double q0 =   a10*c4 - a11*c2 + a13*c0;
        double q1 = -(a00*c4 - a01*c2 + a03*c0);
        double q2 =   a30*s4 - a31*s2 + a33*s0;
        double q3 = -(a20*s4 - a21*s2 + a23*s0);
        xd2 = rdet * (q0*y0 + q1*y1 + q2*y2 + q3*y3);
      }
      {
        double q0 = -(a10*c3 - a11*c1 + a12*c0);
        double q1 =   a00*c3 - a01*c1 + a02*c0;
        double q2 = -(a30*s3 - a31*s1 + a32*s0);
        double q3 =   a20*s3 - a21*s1 + a22*s0;
        xd3 = rdet * (q0*y0 + q1*y1 + q2*y2 + q3*y3);
      }
    } else {
      double G[4][4], V[4][4], rhs[4];
      #pragma unroll
      for (int p = 0; p < 4; ++p) {
        #pragma unroll
        for (int q = 0; q < 4; ++q) {
          double s = 0.0;
          #pragma unroll
          for (int k = 0; k < 4; ++k)
            s += (double)a[p * 4 + k] * (double)a[q * 4 + k];
          G[p][q] = s;
          V[p][q] = (p == q) ? 1.0 : 0.0;
        }
        double s = 0.0;
        #pragma unroll
        for (int k = 0; k < 4; ++k) s += (double)a[p * 4 + k] * (double)a[16 + k];
        rhs[p] = s;
      }
      #pragma unroll
      for (int sweep = 0; sweep < 6; ++sweep) {
        #pragma unroll
        for (int pq = 0; pq < 6; ++pq) {
          constexpr int PP[6] = {0, 0, 0, 1, 1, 2};
          constexpr int QQ[6] = {1, 2, 3, 2, 3, 3};
          const int p = PP[pq], q = QQ[pq];
          double apq = G[p][q];
          double c, s;
          if (apq != 0.0) {
            double tau = (G[q][q] - G[p][p]) / (2.0 * apq);
            double t = (tau >= 0.0 ? 1.0 : -1.0) / (fabs(tau) + sqrt(1.0 + tau * tau));
            c = 1.0 / sqrt(1.0 + t * t);
            s = t * c;
          } else { c = 1.0; s = 0.0; }
          #pragma unroll
          for (int k = 0; k < 4; ++k) {
            double gpk = G[p][k], gqk = G[q][k];
            G[p][k] = c * gpk - s * gqk;
            G[q][k] = s * gpk + c * gqk;
          }
          #pragma unroll
          for (int k = 0; k < 4; ++k) {
            double gkp = G[k][p], gkq = G[k][q];
            G[k][p] = c * gkp - s * gkq;
            G[k][q] = s * gkp + c * gkq;
          }
          #pragma unroll
          for (int k = 0; k < 4; ++k) {
            double vkp = V[k][p], vkq = V[k][q];
            V[k][p] = c * vkp - s * vkq;
            V[k][q] = s * vkp + c * vkq;
          }
        }
      }
      double lam[4] = {G[0][0], G[1][1], G[2][2], G[3][3]};
      double lmax = fmax(fmax(lam[0], lam[1]), fmax(lam[2], lam[3]));
      lmax = fmax(lmax, 0.0);
      const double cut = 2.27373675443232e-11 * lmax;  // (4.7683716e-6)^2
      #pragma unroll
      for (int k = 0; k < 4; ++k) {
        if (lam[k] > cut && lam[k] > 0.0) {
          double coef = (V[0][k] * rhs[0] + V[1][k] * rhs[1] +
                         V[2][k] * rhs[2] + V[3][k] * rhs[3]) / lam[k];
          xd0 += V[0][k] * coef;
          xd1 += V[1][k] * coef;
          xd2 += V[2][k] * coef;
          xd3 += V[3][k] * coef;
        }
      }
    }

    float xls[4];
    {
      double xd[4] = {xd0, xd1, xd2, xd3};
      #pragma unroll
      for (int k = 0; k < 4; ++k) {
        float v = (float)xd[k];
        if (v != v) v = 0.0f;
        v = fminf(fmaxf(v, 0.0f), 1.0f);
        xls[k] = v;
        a[20 + k] = v;
      }
    }

    // ---- scalar f32 MLP (round-4 code) ----
    float acc2[64];
    #pragma unroll
    for (int m = 0; m < 64; ++m) acc2[m] = b2[m];
    for (int j = 0; j < 128; ++j) {
      float t = b1[j];
      #pragma unroll
      for (int k = 0; k < 24; ++k) t = fmaf(a[k], W1[k * 128 + j], t);
      t = fmaxf(t, 0.0f);
      #pragma unroll
      for (int m = 0; m < 64; ++m) acc2[m] = fmaf(t, W2[j * 64 + m], acc2[m]);
    }
    float delta[4] = {b3[0], b3[1], b3[2], b3[3]};
    #pragma unroll
    for (int m = 0; m < 64; ++m) {
      float h = fmaxf(acc2[m], 0.0f);
      #pragma unroll
      for (int c = 0; c < 4; ++c) delta[c] = fmaf(h, W3[m * 4 + c], delta[c]);
    }
    float4 o;
    o.x = fminf(fmaxf(xls[0] + delta[0], 0.0f), 1.0f);
    o.y = fminf(fmaxf(xls[1] + delta[1], 0.0f), 1.0f);
    o.z = fminf(fmaxf(xls[2] + delta[2], 0.0f), 1.0f);
    o.w = fminf(fmaxf(xls[3] + delta[3], 0.0f), 1.0f);
    *(float4*)(out + (long long)g * 4) = o;
  }
}

extern "C" void kernel_launch(void* const* d_in, const int* in_sizes, int n_in,
                              void* d_out, int out_size, void* d_ws, size_t ws_size,
                              hipStream_t stream) {
  (void)n_in;
  const float* x  = (const float*)d_in[0];
  const float* W1 = (const float*)d_in[1];
  const float* b1 = (const float*)d_in[2];
  const float* W2 = (const float*)d_in[3];
  const float* b2 = (const float*)d_in[4];
  const float* W3 = (const float*)d_in[5];
  const float* b3 = (const float*)d_in[6];
  float* out = (float*)d_out;
  const int Bn = in_sizes[0] / 20;

  short* wfrag = nullptr;
  int* wl_cnt = nullptr;
  int* wl_list = nullptr;
  int use_wl = 0;
  if (ws_size >= (size_t)WFRAG_BYTES) wfrag = (short*)d_ws;
  if (ws_size >= (size_t)WL_LIST_OFF + 4ull * (size_t)Bn) {
    wl_cnt  = (int*)((char*)d_ws + WL_CNT_OFF);
    wl_list = (int*)((char*)d_ws + WL_LIST_OFF);
    use_wl = 1;
  }

  (void)hipGetLastError();
  if (wfrag) pack_w<<<7, 256, 0, stream>>>(W1, W2, W3, wfrag, wl_cnt);

  const int nblk = (Bn + 255) / 256;
  MatrixMLP_54047868453544_kernel<<<nblk, 256, 0, stream>>>(
      x, W1, b1, W2, b2, W3, b3, wfrag, wl_cnt, wl_list, out, Bn);

  const int rblk = use_wl ? 256 : (Bn + 255) / 256;
  repair_rows<<<rblk, 256, 0, stream>>>(x, W1, b1, W2, b2, W3, b3, out, Bn,
                                        wl_cnt, wl_list, use_wl);
  hipError_t e = hipGetLastError();
  if (e != hipSuccess) {
    int byte = 0x40 + ((int)e & 63);
    hipMemsetAsync(d_out, byte, (size_t)out_size * sizeof(float), stream);
  }
}

// Round 9
// 159.938 us; speedup vs baseline: 7.9983x; 2.3276x over previous
//
#include <hip/hip_runtime.h>

// MatrixMLP round 9:
//  - Hot kernel: r7 structure; f32 Cramer guarded by |det| > 1e-4*T^2
//    (kappa <= 1e4 -> f32 error ~3e-3; truncation impossible since
//    smin/smax >= |det|/T^2 > 1e-4 >> rcond).  Worklist append now does
//    ONE atomicAdd per wave (ballot+popc+shfl) -- r8's ~8k same-address
//    atomics serialized ~80us of hot-kernel time.
//  - Repair kernel: wave-structured like the hot kernel.  Each wave gathers
//    64 dense worklist rows, runs f64 Jacobi+rcond-truncation for ALL of
//    them lane-parallel (r4-proven semantics), then the SAME MFMA MLP
//    (shared mlp_wave()), scatter-writes.  r8's 235us serial scalar-MLP
//    repair path is gone.

typedef __attribute__((ext_vector_type(8))) short short8;
typedef __attribute__((ext_vector_type(4))) float f32x4;

__device__ __forceinline__ short f2bf(float f) {
  unsigned int u = __float_as_uint(f);
  u += 0x7fffu + ((u >> 16) & 1u);
  return (short)(u >> 16);
}

#define GUARD_THETA 1.0e-4f
#define WFRAG_BYTES 26624        // 26 frags * 64 lanes * 16 B
#define WL_CNT_OFF  26624
#define WL_LIST_OFF 26656
#define RBLK 128                 // repair grid

// ---- per-wave LDS chunk (bytes); strides odd multiples of 16B ----
#define W_A    0        // 64 rows * 80 B
#define W_H1   5120     // 16 rows * 272 B
#define W_H2   9472     // 16 rows * 144 B
#define W_D    11776    // 64 rows * 20 B
#define W_SZ   13056
#define SMEM_SZ (4 * W_SZ)   // 52224 B -> 3 blocks/CU

// ---------------- weight fragment pre-pack (+ worklist counter reset) -------
__global__ void pack_w(const float* __restrict__ W1, const float* __restrict__ W2,
                       const float* __restrict__ W3, short* __restrict__ ws,
                       int* __restrict__ wl_cnt)
{
  if (wl_cnt && blockIdx.x == 0 && threadIdx.x == 0) *wl_cnt = 0;
  int t = blockIdx.x * 256 + threadIdx.x;
  if (t >= 26 * 64) return;
  int fid = t >> 6, lane = t & 63, l15 = lane & 15, lg = lane >> 4;
  short8 v;
  if (fid < 8) {
    int col = fid * 16 + l15;
    #pragma unroll
    for (int j = 0; j < 8; ++j) {
      int k = lg * 8 + j;
      v[j] = (k < 24) ? f2bf(W1[k * 128 + col]) : (short)0;
    }
  } else if (fid < 24) {
    int q = fid - 8, kt = q >> 2, nt = q & 3, col = nt * 16 + l15;
    #pragma unroll
    for (int j = 0; j < 8; ++j)
      v[j] = f2bf(W2[(kt * 32 + lg * 8 + j) * 64 + col]);
  } else {
    int kt = fid - 24;
    #pragma unroll
    for (int j = 0; j < 8; ++j)
      v[j] = (l15 < 4) ? f2bf(W3[(kt * 32 + lg * 8 + j) * 4 + l15]) : (short)0;
  }
  ((short8*)ws)[t] = v;
}

// ---------------- shared wave-autonomous MFMA MLP body ----------------
// Caller must have written all 64 A-rows of this wave's LDS chunk (W_A) and
// may read delta from W_D afterwards.  Loads weights/biases itself (keeps
// the caller's solve-phase VGPR peak low).
__device__ __forceinline__ void mlp_wave(
    unsigned char* wsm, int lane, int l15, int lg,
    const short* __restrict__ wfrag,
    const float* __restrict__ W1, const float* __restrict__ b1,
    const float* __restrict__ W2, const float* __restrict__ b2,
    const float* __restrict__ W3, const float* __restrict__ b3)
{
  const f32x4 fzero = {0.0f, 0.0f, 0.0f, 0.0f};
  const short8* wv4 = (const short8*)wfrag;

  short8 bf1[8];
  if (wfrag) {
    #pragma unroll
    for (int nt = 0; nt < 8; ++nt) bf1[nt] = wv4[nt * 64 + lane];
  } else {
    #pragma unroll
    for (int nt = 0; nt < 8; ++nt) {
      int col = nt * 16 + l15;
      #pragma unroll
      for (int j = 0; j < 8; ++j) {
        int k = lg * 8 + j;
        bf1[nt][j] = (k < 24) ? f2bf(W1[k * 128 + col]) : (short)0;
      }
    }
  }
  float bias1[8], bias2[4], bias3;
  #pragma unroll
  for (int nt = 0; nt < 8; ++nt) bias1[nt] = b1[nt * 16 + l15];
  #pragma unroll
  for (int nt = 0; nt < 4; ++nt) bias2[nt] = b2[nt * 16 + l15];
  bias3 = b3[l15 & 3];

  asm volatile("s_waitcnt lgkmcnt(0)" ::: "memory");  // A-rows visible wave-wide

  for (int t = 0; t < 4; ++t) {
    // layer 1: (16x32)@(32x128) + b1, ReLU -> H1 tile
    {
      short8 a = *(const short8*)(wsm + W_A + (t * 16 + l15) * 80 + lg * 16);
      f32x4 acc[8];
      #pragma unroll
      for (int nt = 0; nt < 8; ++nt)
        acc[nt] = __builtin_amdgcn_mfma_f32_16x16x32_bf16(a, bf1[nt], fzero, 0, 0, 0);
      #pragma unroll
      for (int nt = 0; nt < 8; ++nt) {
        #pragma unroll
        for (int j = 0; j < 4; ++j) {
          float h = acc[nt][j] + bias1[nt];
          h = h > 0.0f ? h : 0.0f;
          *(short*)(wsm + W_H1 + (lg * 4 + j) * 272 + (nt * 16 + l15) * 2) = f2bf(h);
        }
      }
    }
    asm volatile("s_waitcnt lgkmcnt(0)" ::: "memory");

    // layer 2: (16x128)@(128x64) + b2, ReLU -> H2 tile
    {
      f32x4 acc2[4] = {fzero, fzero, fzero, fzero};
      #pragma unroll
      for (int kt = 0; kt < 4; ++kt) {
        short8 a2 = *(const short8*)(wsm + W_H1 + l15 * 272 + kt * 64 + lg * 16);
        #pragma unroll
        for (int nt = 0; nt < 4; ++nt) {
          short8 bw;
          if (wfrag) bw = wv4[(8 + kt * 4 + nt) * 64 + lane];
          else {
            int col = nt * 16 + l15;
            #pragma unroll
            for (int j = 0; j < 8; ++j)
              bw[j] = f2bf(W2[(kt * 32 + lg * 8 + j) * 64 + col]);
          }
          acc2[nt] = __builtin_amdgcn_mfma_f32_16x16x32_bf16(a2, bw, acc2[nt], 0, 0, 0);
        }
      }
      #pragma unroll
      for (int nt = 0; nt < 4; ++nt) {
        #pragma unroll
        for (int j = 0; j < 4; ++j) {
          float h = acc2[nt][j] + bias2[nt];
          h = h > 0.0f ? h : 0.0f;
          *(short*)(wsm + W_H2 + (lg * 4 + j) * 144 + (nt * 16 + l15) * 2) = f2bf(h);
        }
      }
    }
    asm volatile("s_waitcnt lgkmcnt(0)" ::: "memory");

    // layer 3: (16x64)@(64x16[4]) + b3 -> delta
    {
      f32x4 acc3 = fzero;
      #pragma unroll
      for (int kt = 0; kt < 2; ++kt) {
        short8 a3 = *(const short8*)(wsm + W_H2 + l15 * 144 + kt * 64 + lg * 16);
        short8 bw;
        if (wfrag) bw = wv4[(24 + kt) * 64 + lane];
        else {
          #pragma unroll
          for (int j = 0; j < 8; ++j)
            bw[j] = (l15 < 4) ? f2bf(W3[(kt * 32 + lg * 8 + j) * 4 + l15]) : (short)0;
        }
        acc3 = __builtin_amdgcn_mfma_f32_16x16x32_bf16(a3, bw, acc3, 0, 0, 0);
      }
      if (l15 < 4) {
        #pragma unroll
        for (int j = 0; j < 4; ++j)
          *(float*)(wsm + W_D + (t * 16 + lg * 4 + j) * 20 + l15 * 4) = acc3[j] + bias3;
      }
    }
  }
  asm volatile("s_waitcnt lgkmcnt(0)" ::: "memory");  // delta visible
}

// ---------------- hot kernel ----------------
__global__ __launch_bounds__(256, 2) void MatrixMLP_54047868453544_kernel(
    const float* __restrict__ x,
    const float* __restrict__ W1, const float* __restrict__ b1,
    const float* __restrict__ W2, const float* __restrict__ b2,
    const float* __restrict__ W3, const float* __restrict__ b3,
    const short* __restrict__ wfrag,
    int* __restrict__ wl_cnt, int* __restrict__ wl_list,
    float* __restrict__ out, int Bn)
{
  __shared__ __align__(16) unsigned char smem[SMEM_SZ];
  const int tid  = threadIdx.x;
  const int lane = tid & 63;
  const int wv   = tid >> 6;
  const int l15  = lane & 15;
  const int lg   = lane >> 4;
  unsigned char* wsm = smem + wv * W_SZ;
  const long long g = (long long)blockIdx.x * 256 + wv * 64 + lane;

  // ---- load row (1 row/lane) ----
  float xf[20];
  if (g < Bn) {
    const float* xr = x + g * 20;
    #pragma unroll
    for (int i = 0; i < 5; ++i) {
      f32x4 v = *(const f32x4*)(xr + i * 4);
      xf[i*4+0] = v[0]; xf[i*4+1] = v[1]; xf[i*4+2] = v[2]; xf[i*4+3] = v[3];
    }
  } else {
    #pragma unroll
    for (int i = 0; i < 20; ++i) xf[i] = 0.0f;
  }

  // ---- f32 Cramer solve with safety guard (H[i][j] = x[j*4+i]) ----
  float xls[4];
  bool unsafe_row;
  {
    float a00 = xf[0], a01 = xf[4], a02 = xf[8],  a03 = xf[12];
    float a10 = xf[1], a11 = xf[5], a12 = xf[9],  a13 = xf[13];
    float a20 = xf[2], a21 = xf[6], a22 = xf[10], a23 = xf[14];
    float a30 = xf[3], a31 = xf[7], a32 = xf[11], a33 = xf[15];
    float y0 = xf[16], y1 = xf[17], y2 = xf[18], y3 = xf[19];

    float s0 = a00*a11 - a10*a01, s1 = a00*a12 - a10*a02, s2 = a00*a13 - a10*a03;
    float s3 = a01*a12 - a11*a02, s4 = a01*a13 - a11*a03, s5 = a02*a13 - a12*a03;
    float c0 = a20*a31 - a30*a21, c1 = a20*a32 - a30*a22, c2 = a20*a33 - a30*a23;
    float c3 = a21*a32 - a31*a22, c4 = a21*a33 - a31*a23, c5 = a22*a33 - a32*a23;
    float det = s0*c5 - s1*c4 + s2*c3 + s3*c2 - s4*c1 + s5*c0;

    float T = a00*a00 + a01*a01 + a02*a02 + a03*a03
            + a10*a10 + a11*a11 + a12*a12 + a13*a13
            + a20*a20 + a21*a21 + a22*a22 + a23*a23
            + a30*a30 + a31*a31 + a32*a32 + a33*a33;

    const bool safe = __builtin_fabsf(det) > GUARD_THETA * T * T;
    unsafe_row = (!safe) && (g < Bn);
    float xd0 = 0.0f, xd1 = 0.0f, xd2 = 0.0f, xd3 = 0.0f;
    if (safe) {
      float rdet = 1.0f / det;
      {
        float q0 =   a11*c5 - a12*c4 + a13*c3;
        float q1 = -(a01*c5 - a02*c4 + a03*c3);
        float q2 =   a31*s5 - a32*s4 + a33*s3;
        float q3 = -(a21*s5 - a22*s4 + a23*s3);
        xd0 = rdet * (q0*y0 + q1*y1 + q2*y2 + q3*y3);
      }
      {
        float q0 = -(a10*c5 - a12*c2 + a13*c1);
        float q1 =   a00*c5 - a02*c2 + a03*c1;
        float q2 = -(a30*s5 - a32*s2 + a33*s1);
        float q3 =   a20*s5 - a22*s2 + a23*s1;
        xd1 = rdet * (q0*y0 + q1*y1 + q2*y2 + q3*y3);
      }
      {
        float q0 =   a10*c4 - a11*c2 + a13*c0;
        float q1 = -(a00*c4 - a01*c2 + a03*c0);
        float q2 =   a30*s4 - a31*s2 + a33*s0;
        float q3 = -(a20*s4 - a21*s2 + a23*s0);
        xd2 = rdet * (q0*y0 + q1*y1 + q2*y2 + q3*y3);
      }
      {
        float q0 = -(a10*c3 - a11*c1 + a12*c0);
        float q1 =   a00*c3 - a01*c1 + a02*c0;
        float q2 = -(a30*s3 - a31*s1 + a32*s0);
        float q3 =   a20*s3 - a21*s1 + a22*s0;
        xd3 = rdet * (q0*y0 + q1*y1 + q2*y2 + q3*y3);
      }
    }

    float xdv[4] = {xd0, xd1, xd2, xd3};
    short rowbuf[32];
    #pragma unroll
    for (int i = 0; i < 20; ++i) rowbuf[i] = f2bf(xf[i]);
    #pragma unroll
    for (int i = 0; i < 4; ++i) {
      float v = xdv[i];
      if (v != v) v = 0.0f;
      v = fminf(fmaxf(v, 0.0f), 1.0f);
      xls[i] = v;
      rowbuf[20 + i] = f2bf(v);
    }
    #pragma unroll
    for (int i = 24; i < 32; ++i) rowbuf[i] = 0;
    short8* dst = (short8*)(wsm + W_A + lane * 80);
    #pragma unroll
    for (int i = 0; i < 4; ++i) dst[i] = *(short8*)(rowbuf + i * 8);
  }

  // ---- worklist append: ONE atomic per wave (ballot aggregation) ----
  if (wl_list) {
    unsigned long long m = __ballot(unsafe_row);
    if (m) {
      int leader = (int)__builtin_ctzll(m);
      int base = 0;
      if (lane == leader) base = atomicAdd(wl_cnt, (int)__builtin_popcountll(m));
      base = __shfl(base, leader, 64);
      if (unsafe_row) {
        int lt = (int)__builtin_popcountll(m & ((1ull << lane) - 1ull));
        wl_list[base + lt] = (int)g;
      }
    }
  }

  // ---- MFMA MLP over this wave's 64 rows ----
  mlp_wave(wsm, lane, l15, lg, wfrag, W1, b1, W2, b2, W3, b3);

  // ---- epilogue: out = clip(x_ls + delta, 0, 1) ----
  if (g < Bn) {
    const unsigned char* dl = wsm + W_D + lane * 20;
    f32x4 o;
    #pragma unroll
    for (int c = 0; c < 4; ++c) {
      float v = xls[c] + *(const float*)(dl + c * 4);
      o[c] = fminf(fmaxf(v, 0.0f), 1.0f);
    }
    *(f32x4*)(out + g * 4) = o;
  }
}

// ---------------- repair kernel (wave-structured) ----------------
// use_wl=1: each wave gathers 64 dense worklist rows.  use_wl=0 (fallback):
// dense scan; rows failing the hot guard are recomputed, others not written.
// All repair rows take the f64 Jacobi + jax-rcond-truncation path (r4-proven),
// then the same MFMA MLP as the hot kernel.
__global__ __launch_bounds__(256) void repair_rows(
    const float* __restrict__ x,
    const float* __restrict__ W1, const float* __restrict__ b1,
    const float* __restrict__ W2, const float* __restrict__ b2,
    const float* __restrict__ W3, const float* __restrict__ b3,
    const short* __restrict__ wfrag,
    float* __restrict__ out, int Bn,
    const int* __restrict__ wl_cnt, const int* __restrict__ wl_list,
    int use_wl)
{
  __shared__ __align__(16) unsigned char smem[SMEM_SZ];
  const int tid  = threadIdx.x;
  const int lane = tid & 63;
  const int wv   = tid >> 6;
  const int l15  = lane & 15;
  const int lg   = lane >> 4;
  unsigned char* wsm = smem + wv * W_SZ;

  const int count = use_wl ? *wl_cnt : Bn;

  for (long long base = (long long)blockIdx.x * 256 + wv * 64; base < count;
       base += (long long)gridDim.x * 256) {
    const long long idx = base + lane;
    int g = -1;
    if (idx < count) g = use_wl ? wl_list[idx] : (int)idx;

    float xf[20];
    if (g >= 0) {
      const float* xr = x + (long long)g * 20;
      #pragma unroll
      for (int i = 0; i < 5; ++i) {
        f32x4 v = *(const f32x4*)(xr + i * 4);
        xf[i*4+0] = v[0]; xf[i*4+1] = v[1]; xf[i*4+2] = v[2]; xf[i*4+3] = v[3];
      }
    } else {
      #pragma unroll
      for (int i = 0; i < 20; ++i) xf[i] = 0.0f;
    }

    if (!use_wl && g >= 0) {
      // fallback scan: keep only rows failing the hot guard (exact predicate)
      float a00 = xf[0], a01 = xf[4], a02 = xf[8],  a03 = xf[12];
      float a10 = xf[1], a11 = xf[5], a12 = xf[9],  a13 = xf[13];
      float a20 = xf[2], a21 = xf[6], a22 = xf[10], a23 = xf[14];
      float a30 = xf[3], a31 = xf[7], a32 = xf[11], a33 = xf[15];
      float s0 = a00*a11 - a10*a01, s1 = a00*a12 - a10*a02, s2 = a00*a13 - a10*a03;
      float s3 = a01*a12 - a11*a02, s4 = a01*a13 - a11*a03, s5 = a02*a13 - a12*a03;
      float c0 = a20*a31 - a30*a21, c1 = a20*a32 - a30*a22, c2 = a20*a33 - a30*a23;
      float c3 = a21*a32 - a31*a22, c4 = a21*a33 - a31*a23, c5 = a22*a33 - a32*a23;
      float det = s0*c5 - s1*c4 + s2*c3 + s3*c2 - s4*c1 + s5*c0;
      float T = a00*a00 + a01*a01 + a02*a02 + a03*a03
              + a10*a10 + a11*a11 + a12*a12 + a13*a13
              + a20*a20 + a21*a21 + a22*a22 + a23*a23
              + a30*a30 + a31*a31 + a32*a32 + a33*a33;
      if (__builtin_fabsf(det) > GUARD_THETA * T * T) g = -1;
    }

    // ---- f64 Jacobi eigensolve of G = H^T H + jax rcond truncation ----
    double G[4][4], V[4][4], rhs[4];
    #pragma unroll
    for (int p = 0; p < 4; ++p) {
      #pragma unroll
      for (int q = 0; q < 4; ++q) {
        double s = 0.0;
        #pragma unroll
        for (int k = 0; k < 4; ++k)
          s += (double)xf[p * 4 + k] * (double)xf[q * 4 + k];
        G[p][q] = s;
        V[p][q] = (p == q) ? 1.0 : 0.0;
      }
      double s = 0.0;
      #pragma unroll
      for (int k = 0; k < 4; ++k) s += (double)xf[p * 4 + k] * (double)xf[16 + k];
      rhs[p] = s;
    }
    #pragma unroll
    for (int sweep = 0; sweep < 6; ++sweep) {
      #pragma unroll
      for (int pq = 0; pq < 6; ++pq) {
        constexpr int PP[6] = {0, 0, 0, 1, 1, 2};
        constexpr int QQ[6] = {1, 2, 3, 2, 3, 3};
        const int p = PP[pq], q = QQ[pq];
        double apq = G[p][q];
        double c, s;
        if (apq != 0.0) {
          double tau = (G[q][q] - G[p][p]) / (2.0 * apq);
          double t = (tau >= 0.0 ? 1.0 : -1.0) / (fabs(tau) + sqrt(1.0 + tau * tau));
          c = 1.0 / sqrt(1.0 + t * t);
          s = t * c;
        } else { c = 1.0; s = 0.0; }
        #pragma unroll
        for (int k = 0; k < 4; ++k) {
          double gpk = G[p][k], gqk = G[q][k];
          G[p][k] = c * gpk - s * gqk;
          G[q][k] = s * gpk + c * gqk;
        }
        #pragma unroll
        for (int k = 0; k < 4; ++k) {
          double gkp = G[k][p], gkq = G[k][q];
          G[k][p] = c * gkp - s * gkq;
          G[k][q] = s * gkp + c * gkq;
        }
        #pragma unroll
        for (int k = 0; k < 4; ++k) {
          double vkp = V[k][p], vkq = V[k][q];
          V[k][p] = c * vkp - s * vkq;
          V[k][q] = s * vkp + c * vkq;
        }
      }
    }
    double lam[4] = {G[0][0], G[1][1], G[2][2], G[3][3]};
    double lmax = fmax(fmax(lam[0], lam[1]), fmax(lam[2], lam[3]));
    lmax = fmax(lmax, 0.0);
    const double cut = 2.27373675443232e-11 * lmax;  // (4.7683716e-6)^2
    double xd0 = 0.0, xd1 = 0.0, xd2 = 0.0, xd3 = 0.0;
    #pragma unroll
    for (int k = 0; k < 4; ++k) {
      if (lam[k] > cut && lam[k] > 0.0) {
        double coef = (V[0][k] * rhs[0] + V[1][k] * rhs[1] +
                       V[2][k] * rhs[2] + V[3][k] * rhs[3]) / lam[k];
        xd0 += V[0][k] * coef;
        xd1 += V[1][k] * coef;
        xd2 += V[2][k] * coef;
        xd3 += V[3][k] * coef;
      }
    }

    float xls[4];
    {
      double xd[4] = {xd0, xd1, xd2, xd3};
      short rowbuf[32];
      #pragma unroll
      for (int i = 0; i < 20; ++i) rowbuf[i] = f2bf(xf[i]);
      #pragma unroll
      for (int i = 0; i < 4; ++i) {
        float v = (float)xd[i];
        if (v != v) v = 0.0f;
        v = fminf(fmaxf(v, 0.0f), 1.0f);
        xls[i] = v;
        rowbuf[20 + i] = f2bf(v);
      }
      #pragma unroll
      for (int i = 24; i < 32; ++i) rowbuf[i] = 0;
      short8* dst = (short8*)(wsm + W_A + lane * 80);
      #pragma unroll
      for (int i = 0; i < 4; ++i) dst[i] = *(short8*)(rowbuf + i * 8);
    }

    // ---- same MFMA MLP as hot kernel ----
    mlp_wave(wsm, lane, l15, lg, wfrag, W1, b1, W2, b2, W3, b3);

    // ---- scatter epilogue ----
    if (g >= 0) {
      const unsigned char* dl = wsm + W_D + lane * 20;
      f32x4 o;
      #pragma unroll
      for (int c = 0; c < 4; ++c) {
        float v = xls[c] + *(const float*)(dl + c * 4);
        o[c] = fminf(fmaxf(v, 0.0f), 1.0f);
      }
      *(f32x4*)(out + (long long)g * 4) = o;
    }
  }
}

extern "C" void kernel_launch(void* const* d_in, const int* in_sizes, int n_in,
                              void* d_out, int out_size, void* d_ws, size_t ws_size,
                              hipStream_t stream) {
  (void)n_in;
  const float* x  = (const float*)d_in[0];
  const float* W1 = (const float*)d_in[1];
  const float* b1 = (const float*)d_in[2];
  const float* W2 = (const float*)d_in[3];
  const float* b2 = (const float*)d_in[4];
  const float* W3 = (const float*)d_in[5];
  const float* b3 = (const float*)d_in[6];
  float* out = (float*)d_out;
  const int Bn = in_sizes[0] / 20;

  short* wfrag = nullptr;
  int* wl_cnt = nullptr;
  int* wl_list = nullptr;
  int use_wl = 0;
  if (ws_size >= (size_t)WFRAG_BYTES) wfrag = (short*)d_ws;
  if (ws_size >= (size_t)WL_LIST_OFF + 4ull * (size_t)Bn) {
    wl_cnt  = (int*)((char*)d_ws + WL_CNT_OFF);
    wl_list = (int*)((char*)d_ws + WL_LIST_OFF);
    use_wl = 1;
  }

  (void)hipGetLastError();
  if (wfrag) pack_w<<<7, 256, 0, stream>>>(W1, W2, W3, wfrag, wl_cnt);

  const int nblk = (Bn + 255) / 256;
  MatrixMLP_54047868453544_kernel<<<nblk, 256, 0, stream>>>(
      x, W1, b1, W2, b2, W3, b3, wfrag, wl_cnt, wl_list, out, Bn);

  repair_rows<<<RBLK, 256, 0, stream>>>(x, W1, b1, W2, b2, W3, b3, wfrag,
                                        out, Bn, wl_cnt, wl_list, use_wl);
  hipError_t e = hipGetLastError();
  if (e != hipSuccess) {
    int byte = 0x40 + ((int)e & 63);
    hipMemsetAsync(d_out, byte, (size_t)out_size * sizeof(float), stream);
  }
}